// Round 1
// baseline (8398.125 us; speedup 1.0000x reference)
//
#include <hip/hip_runtime.h>
#include <hip/hip_bf16.h>
#include <math.h>
#include <stddef.h>

#define D_MODEL 512
#define NHEAD   8
#define DHEAD   64
#define BATCH   8
#define SEQ     512
#define NLAYER  6
#define DFFN    2048
#define ROWS    (BATCH * SEQ)   // 4096

// ---------------------------------------------------------------------------
// Embedding gather: x[b,t,:] = tgt_emb[tgt_seq[b,t],:] + pos_emb[tgt_pos[b,t],:]
// ---------------------------------------------------------------------------
__global__ __launch_bounds__(128) void embed_kernel(
    const int* __restrict__ seq, const int* __restrict__ pos,
    const float* __restrict__ emb, const float* __restrict__ pemb,
    float* __restrict__ x)
{
    int row = blockIdx.x;                 // 0..4095 = b*512+t
    int tok = seq[row];
    int p   = pos[row];
    const float4* e  = (const float4*)(emb  + (size_t)tok * D_MODEL);
    const float4* pe = (const float4*)(pemb + (size_t)p   * D_MODEL);
    float4* xo = (float4*)(x + (size_t)row * D_MODEL);
    int i = threadIdx.x;                  // 0..127 covers 512 floats
    float4 a = e[i], b = pe[i];
    xo[i] = make_float4(a.x + b.x, a.y + b.y, a.z + b.z, a.w + b.w);
}

// ---------------------------------------------------------------------------
// Generic tiled fp32 GEMM: C = A @ B (+bias)(+relu), optional batching.
//   - 64x64 tile, 256 threads, 4x4 micro-tile, BK=16.
//   - b_head==1: B is (H, D, DK) head-blocked weight; logical col n=(h*64+e),
//                element (k,n) lives at ((n>>6)*512 + k)*64 + (n&63).
//   - batch z: z1=z/zdiv, z2=z%zdiv; base offsets  s1*z1 + s2*z2 per operand.
// Requires M%64==0, N%64==0, K%16==0 (all shapes here comply).
// ---------------------------------------------------------------------------
#define BM 64
#define BN 64
#define BK 16

__global__ __launch_bounds__(256) void gemm_kernel(
    const float* __restrict__ A, const float* __restrict__ B,
    float* __restrict__ C, const float* __restrict__ bias,
    int K, int lda, int ldb, int ldc,
    long a_s1, long a_s2, long b_s1, long b_s2, long c_s1, long c_s2,
    int zdiv, int b_head, int relu)
{
    int z  = blockIdx.z;
    int z1 = z / zdiv, z2 = z % zdiv;
    A += a_s1 * z1 + a_s2 * z2;
    B += b_s1 * z1 + b_s2 * z2;
    C += c_s1 * z1 + c_s2 * z2;

    int row0 = blockIdx.y * BM;
    int col0 = blockIdx.x * BN;

    __shared__ float As[BK][BM + 1];
    __shared__ float Bs[BK][BN + 1];

    int tid = threadIdx.x;
    int tx = tid & 15, ty = tid >> 4;

    // staging index maps
    int a_m  = tid >> 2;          // 0..63
    int a_k4 = (tid & 3) * 4;     // 0,4,8,12
    int b_k  = tid >> 4;          // 0..15
    int b_n4 = (tid & 15) * 4;    // 0..60

    float acc[4][4] = {};

    for (int k0 = 0; k0 < K; k0 += BK) {
        // stage A tile (64 rows x 16 k)
        const float* ap = A + (size_t)(row0 + a_m) * lda + k0 + a_k4;
        float4 av = *(const float4*)ap;
        As[a_k4 + 0][a_m] = av.x;
        As[a_k4 + 1][a_m] = av.y;
        As[a_k4 + 2][a_m] = av.z;
        As[a_k4 + 3][a_m] = av.w;
        // stage B tile (16 k x 64 cols)
        int n  = col0 + b_n4;
        int kk = k0 + b_k;
        const float* bp;
        if (b_head) {
            bp = B + ((size_t)(n >> 6) * D_MODEL + kk) * DHEAD + (n & 63);
        } else {
            bp = B + (size_t)kk * ldb + n;
        }
        float4 bv = *(const float4*)bp;
        Bs[b_k][b_n4 + 0] = bv.x;
        Bs[b_k][b_n4 + 1] = bv.y;
        Bs[b_k][b_n4 + 2] = bv.z;
        Bs[b_k][b_n4 + 3] = bv.w;
        __syncthreads();
        #pragma unroll
        for (int k = 0; k < BK; ++k) {
            float ar[4], br[4];
            #pragma unroll
            for (int i = 0; i < 4; ++i) ar[i] = As[k][ty * 4 + i];
            #pragma unroll
            for (int j = 0; j < 4; ++j) br[j] = Bs[k][tx * 4 + j];
            #pragma unroll
            for (int i = 0; i < 4; ++i)
                #pragma unroll
                for (int j = 0; j < 4; ++j)
                    acc[i][j] += ar[i] * br[j];
        }
        __syncthreads();
    }

    // epilogue
    float bv[4] = {0.f, 0.f, 0.f, 0.f};
    if (bias) {
        #pragma unroll
        for (int j = 0; j < 4; ++j) bv[j] = bias[col0 + tx * 4 + j];
    }
    #pragma unroll
    for (int i = 0; i < 4; ++i) {
        int r = row0 + ty * 4 + i;
        float4 v;
        v.x = acc[i][0] + bv[0];
        v.y = acc[i][1] + bv[1];
        v.z = acc[i][2] + bv[2];
        v.w = acc[i][3] + bv[3];
        if (relu) {
            v.x = fmaxf(v.x, 0.f); v.y = fmaxf(v.y, 0.f);
            v.z = fmaxf(v.z, 0.f); v.w = fmaxf(v.w, 0.f);
        }
        *(float4*)(C + (size_t)r * ldc + col0 + tx * 4) = v;
    }
}

// ---------------------------------------------------------------------------
// Fused attention scores + mask + softmax.
// Block: (q-tile of 16 rows) x (one head-batch hb = h*8+b). 256 threads.
// Writes P (post-softmax probs) directly into the output attn tensor:
//   P[(hb*512 + q)*512 + s]
// causal==1: mask = (seq[b,s]==0) || (s > q);  causal==0: mask = (seq[b,s]==0)
// ---------------------------------------------------------------------------
__global__ __launch_bounds__(256) void attn_softmax_kernel(
    const float* __restrict__ Q, const float* __restrict__ K,
    const int* __restrict__ seq, float* __restrict__ P, int causal)
{
    int hb = blockIdx.y;         // 0..63
    int h  = hb >> 3;
    int b  = hb & 7;
    int q0 = blockIdx.x * 16;

    __shared__ float Qs[16][DHEAD + 1];
    __shared__ float Ks[16][DHEAD + 1];

    int tid = threadIdx.x;
    int tx = tid & 15, ty = tid >> 4;

    // load Q tile: rows q0..q0+15, cols h*64..h*64+63
    {
        int r  = tid >> 4;            // 0..15
        int e4 = (tid & 15) * 4;      // 0..60
        float4 qv = *(const float4*)(Q + ((size_t)(b * SEQ + q0 + r)) * D_MODEL + h * DHEAD + e4);
        Qs[r][e4 + 0] = qv.x; Qs[r][e4 + 1] = qv.y;
        Qs[r][e4 + 2] = qv.z; Qs[r][e4 + 3] = qv.w;
    }

    const float scale = 0.044194173824159216f;   // 1/sqrt(512)
    float logit[32];
    int q = q0 + ty;

    for (int c = 0; c < 32; ++c) {
        int s0 = c * 16;
        __syncthreads();   // covers Qs store (c==0) and previous Ks use (c>0)
        {
            int r  = tid >> 4;
            int e4 = (tid & 15) * 4;
            float4 kv = *(const float4*)(K + ((size_t)(b * SEQ + s0 + r)) * D_MODEL + h * DHEAD + e4);
            Ks[r][e4 + 0] = kv.x; Ks[r][e4 + 1] = kv.y;
            Ks[r][e4 + 2] = kv.z; Ks[r][e4 + 3] = kv.w;
        }
        __syncthreads();
        float dot = 0.f;
        #pragma unroll
        for (int e = 0; e < DHEAD; ++e) dot += Qs[ty][e] * Ks[tx][e];
        int s = s0 + tx;
        bool masked = (seq[b * SEQ + s] == 0);
        if (causal) masked = masked || (s > q);
        logit[c] = masked ? -INFINITY : dot * scale;
    }

    // softmax across 32 regs x 16 threads (threads of a row are 16
    // consecutive lanes; xor-shuffles with mask<16 stay in-group)
    float mx = -INFINITY;
    #pragma unroll
    for (int c = 0; c < 32; ++c) mx = fmaxf(mx, logit[c]);
    #pragma unroll
    for (int m = 1; m < 16; m <<= 1) mx = fmaxf(mx, __shfl_xor(mx, m, 64));
    float sum = 0.f;
    #pragma unroll
    for (int c = 0; c < 32; ++c) {
        float e = __expf(logit[c] - mx);
        logit[c] = e;
        sum += e;
    }
    #pragma unroll
    for (int m = 1; m < 16; m <<= 1) sum += __shfl_xor(sum, m, 64);
    float inv = 1.0f / sum;

    float* prow = P + ((size_t)(hb * SEQ + q)) * SEQ;
    #pragma unroll
    for (int c = 0; c < 32; ++c) prow[c * 16 + tx] = logit[c] * inv;
}

// ---------------------------------------------------------------------------
// Fused residual-add + LayerNorm: out[row] = LN(a[row] + res[row]) * g + b
// One wave (64 lanes) per row, 8 floats per lane.  out may alias res.
// ---------------------------------------------------------------------------
__global__ __launch_bounds__(256) void add_ln_kernel(
    const float* __restrict__ a, const float* __restrict__ res,
    const float* __restrict__ g, const float* __restrict__ bta,
    float* __restrict__ out)
{
    int wave = threadIdx.x >> 6;
    int lane = threadIdx.x & 63;
    int row  = (blockIdx.x << 2) + wave;
    const float* ap = a   + (size_t)row * D_MODEL + lane * 8;
    const float* rp = res + (size_t)row * D_MODEL + lane * 8;
    float4 a0 = *(const float4*)ap;
    float4 a1 = *(const float4*)(ap + 4);
    float4 r0 = *(const float4*)rp;
    float4 r1 = *(const float4*)(rp + 4);
    float v[8];
    v[0] = a0.x + r0.x; v[1] = a0.y + r0.y; v[2] = a0.z + r0.z; v[3] = a0.w + r0.w;
    v[4] = a1.x + r1.x; v[5] = a1.y + r1.y; v[6] = a1.z + r1.z; v[7] = a1.w + r1.w;
    float s = 0.f;
    #pragma unroll
    for (int i = 0; i < 8; ++i) s += v[i];
    #pragma unroll
    for (int m = 1; m < 64; m <<= 1) s += __shfl_xor(s, m, 64);
    float mu = s * (1.0f / 512.0f);
    float vs = 0.f;
    #pragma unroll
    for (int i = 0; i < 8; ++i) { float d = v[i] - mu; vs += d * d; }
    #pragma unroll
    for (int m = 1; m < 64; m <<= 1) vs += __shfl_xor(vs, m, 64);
    float inv = rsqrtf(vs * (1.0f / 512.0f) + 1e-5f);
    int col = lane * 8;
    float o[8];
    #pragma unroll
    for (int i = 0; i < 8; ++i)
        o[i] = (v[i] - mu) * inv * g[col + i] + bta[col + i];
    float4* op = (float4*)(out + (size_t)row * D_MODEL + col);
    op[0] = make_float4(o[0], o[1], o[2], o[3]);
    op[1] = make_float4(o[4], o[5], o[6], o[7]);
}

// ---------------------------------------------------------------------------
__global__ __launch_bounds__(256) void copy_kernel(
    const float4* __restrict__ src, float4* __restrict__ dst, int n4)
{
    int i = blockIdx.x * blockDim.x + threadIdx.x;
    if (i < n4) dst[i] = src[i];
}

// ---------------------------------------------------------------------------
extern "C" void kernel_launch(void* const* d_in, const int* in_sizes, int n_in,
                              void* d_out, int out_size, void* d_ws, size_t ws_size,
                              hipStream_t stream)
{
    (void)in_sizes; (void)n_in; (void)out_size; (void)ws_size;

    const int*   tgt_seq    = (const int*)d_in[0];
    const int*   tgt_pos    = (const int*)d_in[1];
    const int*   src_seq    = (const int*)d_in[2];
    const float* enc_output = (const float*)d_in[3];
    const float* tgt_emb    = (const float*)d_in[4];
    const float* pos_emb    = (const float*)d_in[5];
    const float* slf_wq = (const float*)d_in[6];
    const float* slf_wk = (const float*)d_in[7];
    const float* slf_wv = (const float*)d_in[8];
    const float* slf_pw = (const float*)d_in[9];
    const float* slf_pb = (const float*)d_in[10];
    const float* slf_g  = (const float*)d_in[11];
    const float* slf_b  = (const float*)d_in[12];
    const float* enc_wq = (const float*)d_in[13];
    const float* enc_wk = (const float*)d_in[14];
    const float* enc_wv = (const float*)d_in[15];
    const float* enc_pw = (const float*)d_in[16];
    const float* enc_pb = (const float*)d_in[17];
    const float* enc_g  = (const float*)d_in[18];
    const float* enc_b  = (const float*)d_in[19];
    const float* ffn_w1 = (const float*)d_in[20];
    const float* ffn_b1 = (const float*)d_in[21];
    const float* ffn_w2 = (const float*)d_in[22];
    const float* ffn_b2 = (const float*)d_in[23];
    const float* ffn_g  = (const float*)d_in[24];
    const float* ffn_b  = (const float*)d_in[25];

    float* out = (float*)d_out;

    // workspace layout (floats):  x | qb | kb | vb | hb
    //   qb doubles as attn-output O (Q,K dead by then); kb doubles as tmp.
    float* ws = (float*)d_ws;
    float* x  = ws;                                   // 4096*512
    float* qb = x  + (size_t)ROWS * D_MODEL;          // 4096*512
    float* kb = qb + (size_t)ROWS * D_MODEL;          // 4096*512
    float* vb = kb + (size_t)ROWS * D_MODEL;          // 4096*512
    float* hb = vb + (size_t)ROWS * D_MODEL;          // 4096*2048

    float* ob  = qb;   // attn output buffer (aliases Q)
    float* tmp = kb;   // proj/ffn2 output (aliases K)

    float* slf_attn_out = out + (size_t)ROWS * D_MODEL;
    float* enc_attn_out = slf_attn_out + (size_t)NLAYER * NHEAD * BATCH * SEQ * SEQ;

    const size_t W_STRIDE  = (size_t)NHEAD * D_MODEL * DHEAD;  // 262144
    const size_t PW_STRIDE = (size_t)D_MODEL * D_MODEL;        // 262144
    const size_t ATTN_STRIDE = (size_t)NHEAD * BATCH * SEQ * SEQ;  // 16777216

    embed_kernel<<<ROWS, 128, 0, stream>>>(tgt_seq, tgt_pos, tgt_emb, pos_emb, x);

    // GEMM launch helper (single batch)
    auto gemm1 = [&](const float* A, const float* B, float* C, const float* bias,
                     int M, int N, int K, int lda, int ldb, int ldc,
                     int b_head, int relu) {
        dim3 grid(N / BN, M / BM, 1);
        gemm_kernel<<<grid, 256, 0, stream>>>(A, B, C, bias, K, lda, ldb, ldc,
                                              0, 0, 0, 0, 0, 0, 1, b_head, relu);
    };

    for (int l = 0; l < NLAYER; ++l) {
        // ===================== self-attention =====================
        gemm1(x, slf_wq + l * W_STRIDE, qb, nullptr, ROWS, D_MODEL, D_MODEL, 512, 0, 512, 1, 0);
        gemm1(x, slf_wk + l * W_STRIDE, kb, nullptr, ROWS, D_MODEL, D_MODEL, 512, 0, 512, 1, 0);
        gemm1(x, slf_wv + l * W_STRIDE, vb, nullptr, ROWS, D_MODEL, D_MODEL, 512, 0, 512, 1, 0);
        float* P = slf_attn_out + (size_t)l * ATTN_STRIDE;
        attn_softmax_kernel<<<dim3(SEQ / 16, NHEAD * BATCH), 256, 0, stream>>>(
            qb, kb, tgt_seq, P, 1);
        // O[b,q,h,e] = sum_s P[hb,q,s] * V[b,s,h,e]   (batched over hb)
        {
            dim3 grid(DHEAD / BN, SEQ / BM, NHEAD * BATCH);
            gemm_kernel<<<grid, 256, 0, stream>>>(
                P, vb, ob, nullptr, SEQ, 512, 512, 512,
                /*a_s1(h)*/ (long)BATCH * SEQ * SEQ, /*a_s2(b)*/ (long)SEQ * SEQ,
                /*b_s1(h)*/ DHEAD, /*b_s2(b)*/ (long)SEQ * D_MODEL,
                /*c_s1(h)*/ DHEAD, /*c_s2(b)*/ (long)SEQ * D_MODEL,
                /*zdiv*/ BATCH, 0, 0);
        }
        gemm1(ob, slf_pw + l * PW_STRIDE, tmp, slf_pb + l * D_MODEL,
              ROWS, D_MODEL, D_MODEL, 512, 512, 512, 0, 0);
        add_ln_kernel<<<ROWS / 4, 256, 0, stream>>>(tmp, x, slf_g + l * D_MODEL,
                                                    slf_b + l * D_MODEL, x);

        // ===================== cross-attention =====================
        gemm1(x,          enc_wq + l * W_STRIDE, qb, nullptr, ROWS, D_MODEL, D_MODEL, 512, 0, 512, 1, 0);
        gemm1(enc_output, enc_wk + l * W_STRIDE, kb, nullptr, ROWS, D_MODEL, D_MODEL, 512, 0, 512, 1, 0);
        gemm1(enc_output, enc_wv + l * W_STRIDE, vb, nullptr, ROWS, D_MODEL, D_MODEL, 512, 0, 512, 1, 0);
        P = enc_attn_out + (size_t)l * ATTN_STRIDE;
        attn_softmax_kernel<<<dim3(SEQ / 16, NHEAD * BATCH), 256, 0, stream>>>(
            qb, kb, src_seq, P, 0);
        {
            dim3 grid(DHEAD / BN, SEQ / BM, NHEAD * BATCH);
            gemm_kernel<<<grid, 256, 0, stream>>>(
                P, vb, ob, nullptr, SEQ, 512, 512, 512,
                (long)BATCH * SEQ * SEQ, (long)SEQ * SEQ,
                DHEAD, (long)SEQ * D_MODEL,
                DHEAD, (long)SEQ * D_MODEL,
                BATCH, 0, 0);
        }
        gemm1(ob, enc_pw + l * PW_STRIDE, tmp, enc_pb + l * D_MODEL,
              ROWS, D_MODEL, D_MODEL, 512, 512, 512, 0, 0);
        add_ln_kernel<<<ROWS / 4, 256, 0, stream>>>(tmp, x, enc_g + l * D_MODEL,
                                                    enc_b + l * D_MODEL, x);

        // ===================== FFN =====================
        gemm1(x, ffn_w1 + (size_t)l * D_MODEL * DFFN, hb, ffn_b1 + l * DFFN,
              ROWS, DFFN, D_MODEL, 512, DFFN, DFFN, 0, 1);
        gemm1(hb, ffn_w2 + (size_t)l * DFFN * D_MODEL, tmp, ffn_b2 + l * D_MODEL,
              ROWS, D_MODEL, DFFN, DFFN, 512, 512, 0, 0);
        add_ln_kernel<<<ROWS / 4, 256, 0, stream>>>(tmp, x, ffn_g + l * D_MODEL,
                                                    ffn_b + l * D_MODEL, x);
    }

    // final x -> d_out[0 : ROWS*D_MODEL]
    int n4 = ROWS * D_MODEL / 4;
    copy_kernel<<<(n4 + 255) / 256, 256, 0, stream>>>((const float4*)x, (float4*)out, n4);
}